// Round 15
// baseline (251.483 us; speedup 1.0000x reference)
//
#include <hip/hip_runtime.h>
#include <stdint.h>

typedef unsigned short u16;
typedef __bf16 bf16x8 __attribute__((ext_vector_type(8)));
typedef float  f32x4  __attribute__((ext_vector_type(4)));

// ---- problem constants ----
#define SDIM 2048
#define BDIM 8
#define DIN  1024
#define DOUT 4096
#define EDIM 8
#define RDIM 16
#define KAUG 1152            // DIN + E*R
#define MDIM (SDIM*BDIM)     // 16384
#define SCH  32
#define NT2  18              // K-tiles of 64 for the main GEMM
#define NCB  (DOUT/16)       // 256 col-blocks in WaugF
#define NKC  (KAUG/8)        // 144 k-chunks in WaugF

__device__ __forceinline__ u16 f2bf(float f) {
    __bf16 h = (__bf16)f;
    return __builtin_bit_cast(u16, h);
}

__device__ __forceinline__ void gload16(const u16* g, u16* lds) {
    __builtin_amdgcn_global_load_lds(
        (const __attribute__((address_space(1))) void*)g,
        (__attribute__((address_space(3))) void*)lds, 16, 0, 0);
}

#define VMCNT(n)  asm volatile("s_waitcnt vmcnt(" #n ")" ::: "memory")
#define BARF()    do { asm volatile("" ::: "memory");                \
                       __builtin_amdgcn_s_barrier();                 \
                       asm volatile("" ::: "memory"); } while (0)

// ---------------------------------------------------------------------------
// k1: per-(b, s-chunk) partial sums of x over s + bf16 convert into Xb
// ---------------------------------------------------------------------------
__global__ __launch_bounds__(256) void k1_reduce_convert(
    const float* __restrict__ x, u16* __restrict__ Xb, float* __restrict__ P)
{
    const int b  = blockIdx.x;
    const int sc = blockIdx.y;
    const int i  = threadIdx.x * 4;
    float a0 = 0.f, a1 = 0.f, a2 = 0.f, a3 = 0.f;
    const int s0 = sc * (SDIM / SCH);
    for (int s = s0; s < s0 + (SDIM / SCH); ++s) {
        const float4 v = *reinterpret_cast<const float4*>(
            &x[((size_t)s * BDIM + b) * DIN + i]);
        a0 += v.x; a1 += v.y; a2 += v.z; a3 += v.w;
        ushort4 u{f2bf(v.x), f2bf(v.y), f2bf(v.z), f2bf(v.w)};
        *reinterpret_cast<ushort4*>(&Xb[((size_t)s * BDIM + b) * KAUG + i]) = u;
    }
    float4 p{a0, a1, a2, a3};
    *reinterpret_cast<float4*>(&P[((size_t)sc * BDIM + b) * DIN + i]) = p;
}

// ---------------------------------------------------------------------------
// k2: gate weights
// ---------------------------------------------------------------------------
__global__ __launch_bounds__(256) void k2_gates(
    const float* __restrict__ P, const float* __restrict__ gw,
    const float* __restrict__ gb, float* __restrict__ g)
{
    const int e = blockIdx.x, b = blockIdx.y, t = threadIdx.x;
    float dot = 0.f;
    for (int i = t; i < DIN; i += 256) {
        float xs = 0.f;
        #pragma unroll
        for (int c = 0; c < SCH; ++c) xs += P[((size_t)c * BDIM + b) * DIN + i];
        dot += xs * gw[(size_t)e * DIN + i];
    }
    __shared__ float red[256];
    red[t] = dot;
    __syncthreads();
    #pragma unroll
    for (int off = 128; off > 0; off >>= 1) {
        if (t < off) red[t] += red[t + off];
        __syncthreads();
    }
    if (t == 0) g[b * EDIM + e] = red[0] * (1.0f / SDIM) + gb[e];
}

// ---------------------------------------------------------------------------
// kwf: build pre-fragmented WaugF[cb][kc][ln] (16B entries = B MFMA frags).
//   kc <  128: entry = bf16(W[cb*16+ln][kc*8 .. +8])
//   kc >= 128: e=(kc-128)>>1, rh=(kc-128)&1:
//              entry = bf16(lora_B[e][cb*16+ln][rh*8 .. +8])
// grid 256 (cb), 256 thr: t -> (ln = t&15, kc = t>>4 + 16*b), b=0..8.
// ---------------------------------------------------------------------------
__global__ __launch_bounds__(256) void kwf_build_waugf(
    const float* __restrict__ W, const float* __restrict__ lb, u16* __restrict__ WF)
{
    const int cb = blockIdx.x, t = threadIdx.x;
    const int ln = t & 15;
    const int o  = cb * 16 + ln;
    #pragma unroll
    for (int bq = 0; bq < 9; ++bq) {
        const int kc = (t >> 4) + 16 * bq;   // 0..143
        u16 v[8];
        if (kc < 128) {
            #pragma unroll
            for (int q = 0; q < 8; ++q)
                v[q] = f2bf(W[(size_t)o * DIN + kc * 8 + q]);
        } else {
            const int e = (kc - 128) >> 1, rh = (kc - 128) & 1;
            #pragma unroll
            for (int q = 0; q < 8; ++q)
                v[q] = f2bf(lb[((size_t)e * DOUT + o) * RDIM + rh * 8 + q]);
        }
        u16* dst = WF + (((size_t)cb * NKC + kc) * 16 + ln) * 8;
        *reinterpret_cast<ushort4*>(dst)     = ushort4{v[0], v[1], v[2], v[3]};
        *reinterpret_cast<ushort4*>(dst + 4) = ushort4{v[4], v[5], v[6], v[7]};
    }
}

__global__ __launch_bounds__(256) void kl_convert(
    const float* __restrict__ la, u16* __restrict__ LAb)
{
    const int idx = blockIdx.x * 256 + threadIdx.x;
    if (idx < EDIM * RDIM * DIN) LAb[idx] = f2bf(la[idx]);
}

// ---------------------------------------------------------------------------
// gemm_lora: t = Xb(:, :1024) * LAb^T, fused epilogue u = bf16(g*t) written
// directly into Xb cols [1024,1152). 128x128 tile, BK=64, R6 layout.
// ---------------------------------------------------------------------------
__global__ __launch_bounds__(256) void gemm_lora(
    const u16* __restrict__ A, const u16* __restrict__ B,
    const float* __restrict__ G, u16* __restrict__ Xb)
{
    __shared__ __align__(16) u16 As[128][64];
    __shared__ __align__(16) u16 Bs[128][64];

    const int tid  = threadIdx.x;
    const int lane = tid & 63;
    const int l15  = lane & 15;
    const int l4   = lane >> 4;
    const int sw   = lane & 7;
    const int wid  = tid >> 6;
    const int wr   = wid >> 1;
    const int wc   = wid & 1;
    const int m0 = blockIdx.y * 128;

    f32x4 acc[4][4] = {};

    for (int kt = 0; kt < DIN / 64; ++kt) {
        #pragma unroll
        for (int ii = 0; ii < 4; ++ii) {
            const int cix = ii * 256 + tid;
            const int row = cix >> 3, cl = cix & 7;
            const int kof = kt * 64 + ((cl ^ (row & 7)) << 3);
            gload16(A + (size_t)(m0 + row) * KAUG + kof, &As[0][0] + cix * 8);
            gload16(B + (size_t)row * DIN + kof, &Bs[0][0] + cix * 8);
        }
        __syncthreads();
        #pragma unroll
        for (int ks = 0; ks < 2; ++ks) {
            bf16x8 av[4], bv[4];
            #pragma unroll
            for (int mi = 0; mi < 4; ++mi)
                av[mi] = *reinterpret_cast<const bf16x8*>(
                    &As[wr * 64 + mi * 16 + l15][((ks * 4 + l4) ^ sw) << 3]);
            #pragma unroll
            for (int ni = 0; ni < 4; ++ni)
                bv[ni] = *reinterpret_cast<const bf16x8*>(
                    &Bs[wc * 64 + ni * 16 + l15][((ks * 4 + l4) ^ sw) << 3]);
            #pragma unroll
            for (int mi = 0; mi < 4; ++mi)
                #pragma unroll
                for (int ni = 0; ni < 4; ++ni)
                    acc[mi][ni] = __builtin_amdgcn_mfma_f32_16x16x32_bf16(
                        av[mi], bv[ni], acc[mi][ni], 0, 0, 0);
        }
        __syncthreads();
    }

    #pragma unroll
    for (int mi = 0; mi < 4; ++mi) {
        const int r0 = m0 + wr * 64 + mi * 16 + l4 * 4;
        #pragma unroll
        for (int ni = 0; ni < 4; ++ni) {
            const int col = wc * 64 + ni * 16 + l15;   // 0..127
            const int e   = col >> 4;
            #pragma unroll
            for (int r = 0; r < 4; ++r) {
                const int row = r0 + r;
                const float gv = G[((row & 7) << 3) + e];
                Xb[(size_t)row * KAUG + DIN + col] = f2bf(gv * acc[mi][ni][r]);
            }
        }
    }
}

// ---------------------------------------------------------------------------
// gemm_main R14: B DIRECT-FROM-GLOBAL (pre-fragmented WaugF), A-only LDS.
// Rationale: R8-R13 pinned at 170us = MFMA 2483 + LDS-port ~2800 cyc/K-tile
// serialized. Removing B from LDS cuts LDS traffic to ~1500 cyc/K-tile
// (< MFMA) and moves B to the parallel VMEM pipe (L2-resident, supertile).
// BM=BN=256, BK=64, 512 thr (8 waves 2Mx4N), A dbuf LDS 64 KiB (R8 layout),
// supertile XCD mapping, 2 phases/K-tile, R8-style 1-barrier phases.
// B prefetch: lead-1 tile, double-banked regs (bvE/bvO, static unroll).
//   TILE(T, BVU, BVL): pA: rd q0; stageA(T+1,h0); BLOAD(T+1,kk0)->BVL;
//                          MFMA q0; rd q1; MFMA q1; bar
//                      pB: rd q2; stageA(T+1,h1); BLOAD(T+1,kk1)->BVL;
//                          MFMA q2; rd q3; MFMA q3; VMCNT(0); bar
// Gate: single VMCNT(0) per K-tile AFTER the 32-MFMA pB cluster — the
// drained loads were issued >= 1 phase (~1700 cyc) earlier, so the drain is
// ~free; it guarantees A(T+1) LDS (both halves) before any wave reads it at
// pA(T+1). B-register readiness is enforced by compiler auto-waitcnt (loads
// land 1-2 phases before use). WAR: stageA(T+1,h) overwrites buf regions
// last read at pB(T-1), >= 1 barrier upstream. All guards: if (T+1 < NT2).
// ---------------------------------------------------------------------------
__global__ __launch_bounds__(512) void gemm_main(
    const u16* __restrict__ A, const u16* __restrict__ WF,
    float* __restrict__ C, const float* __restrict__ bias)
{
    __shared__ __align__(16) u16 As[2][2][128][64];   // [buf][Mhalf][row][k] 64 KiB

    const int tid  = threadIdx.x;
    const int lane = tid & 63;
    const int l15  = lane & 15;
    const int l4   = lane >> 4;
    const int sw   = lane & 7;
    const int wid  = tid >> 6;      // 0..7
    const int wm   = wid >> 2;      // 0..1  (128-row half)
    const int wn   = wid & 3;       // 0..3  (64-col quarter)

    // supertile XCD mapping (R12-verified: FETCH 166->110 MB)
    const int f   = blockIdx.x + blockIdx.y * gridDim.x;
    const int xcd = f & 7, kk_ = f >> 3;
    const int gn  = xcd & 3, gm = xcd >> 2;
    const int n0  = (gn * 4 + (kk_ & 3)) * 256;
    const int m0  = (gm * 32 + (kk_ >> 2)) * 256;

    const int cb0 = (n0 >> 4) + wn * 4;   // wave's col-block base in WaugF

    f32x4  acc[8][4] = {};
    bf16x8 aq[2][2];
    bf16x8 bvE[4][2], bvO[4][2];

    auto stageA = [&](int t, int hf) {
        const int buf = t & 1;
        #pragma unroll
        for (int ii = 0; ii < 2; ++ii) {
            const int cix = ii * 512 + tid;
            const int row = cix >> 3, cl = cix & 7;
            const int kof = t * 64 + ((cl ^ (row & 7)) << 3);
            gload16(A + (size_t)(m0 + hf * 128 + row) * KAUG + kof,
                    &As[buf][hf][0][0] + cix * 8);
        }
    };

    // B fragment load: tile T, k-half KK -> bank[nf][KK]
    #define BLOAD(T, KK, BANK)                                                \
        _Pragma("unroll") for (int nf = 0; nf < 4; ++nf)                      \
            BANK[nf][KK] = *reinterpret_cast<const bf16x8*>(                  \
                WF + (((size_t)(cb0 + nf) * NKC + ((T) * 8 + (KK) * 4 + l4))  \
                      * 16 + l15) * 8);
    #define RD_AQ(BUF, Q)                                                     \
        _Pragma("unroll") for (int fr = 0; fr < 2; ++fr)                      \
            _Pragma("unroll") for (int kk = 0; kk < 2; ++kk)                  \
                aq[fr][kk] = *reinterpret_cast<const bf16x8*>(                \
                    &As[BUF][wm][(Q) * 32 + fr * 16 + l15]                    \
                       [((kk * 4 + l4) ^ sw) << 3]);
    #define MMA(Q, BANK)                                                      \
        do {                                                                  \
            __builtin_amdgcn_s_setprio(1);                                    \
            _Pragma("unroll") for (int kk = 0; kk < 2; ++kk)                  \
                _Pragma("unroll") for (int fr = 0; fr < 2; ++fr)              \
                    _Pragma("unroll") for (int nf = 0; nf < 4; ++nf)          \
                        acc[(Q) * 2 + fr][nf] =                               \
                            __builtin_amdgcn_mfma_f32_16x16x32_bf16(          \
                                aq[fr][kk], BANK[nf][kk],                     \
                                acc[(Q) * 2 + fr][nf], 0, 0, 0);              \
            __builtin_amdgcn_s_setprio(0);                                    \
        } while (0)

    // TILE body: consume tile T (A from LDS buf T&1, B from BVU);
    // prefetch A(T+1) into LDS and B(T+1) into BVL.
    #define TILE(T, BVU, BVL)                                                 \
    do {                                                                      \
        const int buf_ = (T) & 1;                                             \
        /* ---- pA: quadrants 0,1 ---- */                                     \
        RD_AQ(buf_, 0);                                                       \
        if ((T) + 1 < NT2) { stageA((T) + 1, 0); BLOAD((T) + 1, 0, BVL); }    \
        MMA(0, BVU);                                                          \
        RD_AQ(buf_, 1);                                                       \
        MMA(1, BVU);                                                          \
        BARF();                                                               \
        /* ---- pB: quadrants 2,3 ---- */                                     \
        RD_AQ(buf_, 2);                                                       \
        if ((T) + 1 < NT2) { stageA((T) + 1, 1); BLOAD((T) + 1, 1, BVL); }    \
        MMA(2, BVU);                                                          \
        RD_AQ(buf_, 3);                                                       \
        MMA(3, BVU);                                                          \
        VMCNT(0);                                                             \
        BARF();                                                               \
    } while (0)

    // prologue: A(0) both halves staged; B(0) -> bvE; drain; barrier.
    stageA(0, 0); stageA(0, 1);
    BLOAD(0, 0, bvE); BLOAD(0, 1, bvE);
    VMCNT(0);
    BARF();

    for (int jj = 0; jj < NT2; jj += 2) {
        TILE(jj,     bvE, bvO);
        TILE(jj + 1, bvO, bvE);
    }
    #undef TILE
    #undef MMA
    #undef RD_AQ
    #undef BLOAD

    // ---- epilogue: row = wm*128 + a*16 + l4*4, col per fragment ----
    #pragma unroll
    for (int a = 0; a < 8; ++a) {
        const int row0 = m0 + wm * 128 + a * 16 + l4 * 4;
        #pragma unroll
        for (int nf = 0; nf < 4; ++nf) {
            const int col = n0 + wn * 64 + nf * 16 + l15;
            const float badd = bias[col];
            float* cp = C + (size_t)row0 * DOUT + col;
            #pragma unroll
            for (int q = 0; q < 4; ++q)
                cp[(size_t)q * DOUT] = acc[a][nf][q] + badd;
        }
    }
}

// ---------------------------------------------------------------------------
extern "C" void kernel_launch(void* const* d_in, const int* in_sizes, int n_in,
                              void* d_out, int out_size, void* d_ws, size_t ws_size,
                              hipStream_t stream)
{
    const float* x    = (const float*)d_in[0];
    const float* gw   = (const float*)d_in[1];
    const float* gb   = (const float*)d_in[2];
    const float* W    = (const float*)d_in[3];
    const float* bias = (const float*)d_in[4];
    const float* la   = (const float*)d_in[5];
    const float* lb   = (const float*)d_in[6];
    float* out = (float*)d_out;

    char* ws = (char*)d_ws;
    u16*   Xb   = (u16*)(ws);                       // 37,748,736 B
    u16*   WF   = (u16*)(ws + 37748736);            //  9,437,184 B (WaugF)
    float* P    = (float*)(ws + 47185920);          //  1,048,576 B
    u16*   LAb  = (u16*)(ws + 48234496);            //    262,144 B
    float* G    = (float*)(ws + 48496640);          //        256 B

    k1_reduce_convert<<<dim3(BDIM, SCH), 256, 0, stream>>>(x, Xb, P);
    kwf_build_waugf<<<NCB, 256, 0, stream>>>(W, lb, WF);
    kl_convert<<<(EDIM * RDIM * DIN + 255) / 256, 256, 0, stream>>>(la, LAb);
    k2_gates<<<dim3(EDIM, BDIM), 256, 0, stream>>>(P, gw, gb, G);
    gemm_lora<<<dim3(1, MDIM / 128), 256, 0, stream>>>(Xb, LAb, G, Xb);
    gemm_main<<<dim3(DOUT / 256, MDIM / 256), 512, 0, stream>>>(
        Xb, WF, out, bias);
}